// Round 1
// baseline (3006.069 us; speedup 1.0000x reference)
//
#include <hip/hip_runtime.h>
#include <stdint.h>

// LatticeLSTM on MI355X.
// Phase 1 (parallel): Xg = x@Wih+b, Xa = x@aWih+ab, Wgx = emb[prod_word]@wWih+wb.
// Phase 2 (sequential): persistent 32-WG kernel, register-resident recurrent
// weights, column-split over H (16 elems/WG), custom agent-scope spin barriers.

#define T_LEN 512
#define D_IN  256
#define H_DIM 512
#define G3    1536
#define M_TOT 340
#define NWG   32
#define NT    512
#define CH    16     // H elements owned per WG
#define NC3   48     // gate columns per WG (3 * CH)

__device__ __forceinline__ float sigf(float x) { return 1.0f / (1.0f + __expf(-x)); }

__device__ __forceinline__ float red8(float a) {
  a += __shfl_down(a, 4);
  a += __shfl_down(a, 2);
  a += __shfl_down(a, 1);
  return a;
}

// Inter-workgroup barrier: monotonically increasing counter, agent scope.
__device__ __forceinline__ void gbar(unsigned* cnt, unsigned target) {
  __syncthreads();
  if (threadIdx.x == 0) {
    __threadfence();  // release: flush our global writes to agent-coherent point
    __hip_atomic_fetch_add(cnt, 1u, __ATOMIC_RELAXED, __HIP_MEMORY_SCOPE_AGENT);
    while (__hip_atomic_load(cnt, __ATOMIC_RELAXED, __HIP_MEMORY_SCOPE_AGENT) < target) {
      __builtin_amdgcn_s_sleep(1);
    }
    __threadfence();  // acquire: invalidate stale cached lines
  }
  __syncthreads();
}

// out[r][c] = bias[c] + sum_k A[src(r)][k] * W[k][c],  K fixed at 256.
template <int RT>
__global__ void proj_kernel(const float* __restrict__ A, const float* __restrict__ W,
                            const float* __restrict__ bias, float* __restrict__ out,
                            const int* __restrict__ gather, int N) {
  __shared__ float As[RT][256];
  const int tid = threadIdx.x;
  const int rt = blockIdx.x * RT;
  const int c = blockIdx.y * 256 + tid;
  for (int rr = 0; rr < RT; ++rr) {
    int r = rt + rr;
    int src = gather ? gather[r] : r;
    As[rr][tid] = A[(long)src * 256 + tid];
  }
  __syncthreads();
  float acc[RT];
#pragma unroll
  for (int rr = 0; rr < RT; ++rr) acc[rr] = 0.f;
  for (int k = 0; k < 256; ++k) {
    float wv = W[k * N + c];
#pragma unroll
    for (int rr = 0; rr < RT; ++rr) acc[rr] += As[rr][k] * wv;
  }
  float b = bias[c];
#pragma unroll
  for (int rr = 0; rr < RT; ++rr) out[(rt + rr) * N + c] = acc[rr] + b;
}

__global__ __launch_bounds__(NT, 1) void lattice_seq(
    const float* __restrict__ Whh,   // 512 x 1536
    const float* __restrict__ aWhh,  // 512 x 512
    const float* __restrict__ wWhh,  // 512 x 1536
    const float* __restrict__ Xg,    // T x 1536 (includes bias)
    const float* __restrict__ Xa,    // T x 512  (includes alpha_bias)
    const float* __restrict__ Wgx,   // (T*2) x 1536 (includes w_bias)
    const int* __restrict__ prod_mask, const int* __restrict__ prod_dest,
    const int* __restrict__ cons_idx,  const int* __restrict__ cons_mask,
    float* __restrict__ Hbuf,   // T x 512
    float* __restrict__ store,  // (M+1) x 512, zeroed before launch
    unsigned* __restrict__ cnt, // zeroed before launch
    float* __restrict__ out)    // hs at [0,T*H), cs at [T*H, 2*T*H)
{
  const int tid = threadIdx.x;
  const int w = blockIdx.x;
  const int j0 = w * CH;

  __shared__ float h1s[H_DIM];
  __shared__ float prevc1[CH];
  __shared__ float ds_g[NC3];
  __shared__ float ds_wg[NC3];
  __shared__ float ds_a[2 * CH];

  // Register-resident weight slices.
  // tid < 384: role A/B. lane = col*8 + ks; col in [0,48), ks in [0,8).
  //   wreg[0:64]  = Whh rows {ks*4 + u*32 + v} of column gcol
  //   wreg[64:128]= wWhh same
  // tid >= 384: role C. lane' = cc*8 + ks; cc in [0,16).
  //   wreg[0:64]  = aWhh rows {ks*4 + u*32 + v} of column j0+cc
  float wreg[128];
  int col, ks;
  if (tid < 384) {
    col = tid >> 3; ks = tid & 7;
    int gcol = (col >> 4) * 512 + j0 + (col & 15);
#pragma unroll
    for (int u = 0; u < 16; ++u)
#pragma unroll
      for (int v = 0; v < 4; ++v) {
        int r = ks * 4 + u * 32 + v;
        wreg[u * 4 + v]      = Whh[r * G3 + gcol];
        wreg[64 + u * 4 + v] = wWhh[r * G3 + gcol];
      }
  } else {
    col = (tid - 384) >> 3; ks = (tid - 384) & 7;
    int gcol = j0 + col;
#pragma unroll
    for (int u = 0; u < 16; ++u)
#pragma unroll
      for (int v = 0; v < 4; ++v) {
        int r = ks * 4 + u * 32 + v;
        wreg[u * 4 + v]      = aWhh[r * H_DIM + gcol];
        wreg[64 + u * 4 + v] = 0.f;
      }
  }
  h1s[tid] = 0.f;
  if (tid < CH) prevc1[tid] = 0.f;
  __syncthreads();

  unsigned bc = 0;

  for (int e = 0; e < T_LEN; ++e) {
    const int p = e - 1;
    const bool prodp = (p >= 0) && ((prod_mask[p * 2] | prod_mask[p * 2 + 1]) != 0);
    const bool conse = (cons_mask[e * 2] | cons_mask[e * 2 + 1]) != 0;

    // ---- Phase A: finalize word cells produced at step p (needs full h1[p]).
    if (prodp) {
      if (tid < 384) {
        float acc = 0.f;
#pragma unroll
        for (int u = 0; u < 16; ++u) {
          float4 hv = *(const float4*)&h1s[ks * 4 + u * 32];
          acc += hv.x * wreg[64 + u * 4] + hv.y * wreg[64 + u * 4 + 1]
               + hv.z * wreg[64 + u * 4 + 2] + hv.w * wreg[64 + u * 4 + 3];
        }
        acc = red8(acc);
        if (ks == 0) ds_wg[col] = acc;
      }
      __syncthreads();
      if (tid < 32) {
        const int k = tid >> 4, jj = tid & 15;
        if (prod_mask[p * 2 + k]) {
          const int r = p * 2 + k;
          float f2 = Wgx[r * G3 + (j0 + jj)]        + ds_wg[jj];
          float i2 = Wgx[r * G3 + 512  + (j0 + jj)] + ds_wg[16 + jj];
          float g2 = Wgx[r * G3 + 1024 + (j0 + jj)] + ds_wg[32 + jj];
          float ct = sigf(f2) * prevc1[jj] + sigf(i2) * tanhf(g2);
          store[prod_dest[r] * H_DIM + (j0 + jj)] = ct;
        }
      }
      if (conse) gbar(cnt, ++bc * NWG);  // lag-1 consume: store must be visible
      else __syncthreads();
    }

    // ---- Phase B: recurrent matvecs for step e.
    if (tid < 384) {  // gates = h1[e-1] @ Whh columns
      float acc = 0.f;
#pragma unroll
      for (int u = 0; u < 16; ++u) {
        float4 hv = *(const float4*)&h1s[ks * 4 + u * 32];
        acc += hv.x * wreg[u * 4] + hv.y * wreg[u * 4 + 1]
             + hv.z * wreg[u * 4 + 2] + hv.w * wreg[u * 4 + 3];
      }
      acc = red8(acc);
      if (ks == 0) ds_g[col] = acc;
    } else if (conse) {  // alpha pre-act: c_in[k] @ aWhh columns
      for (int k = 0; k < 2; ++k) {
        const int m = cons_idx[e * 2 + k];
        const float4* row = (const float4*)&store[m * H_DIM];
        float acc = 0.f;
#pragma unroll
        for (int u = 0; u < 16; ++u) {
          float4 cv = row[ks + u * 8];
          acc += cv.x * wreg[u * 4] + cv.y * wreg[u * 4 + 1]
               + cv.z * wreg[u * 4 + 2] + cv.w * wreg[u * 4 + 3];
        }
        acc = red8(acc);
        if (ks == 0) ds_a[k * CH + col] = acc;
      }
    }
    __syncthreads();

    // ---- Phase C: elementwise combine for owned H-chunk.
    if (tid < CH) {
      const int j = j0 + tid;
      float ipre = Xg[e * G3 + j]        + ds_g[tid];
      float opre = Xg[e * G3 + 512 + j]  + ds_g[16 + tid];
      float gpre = Xg[e * G3 + 1024 + j] + ds_g[32 + tid];
      float iv = sigf(ipre), ov = sigf(opre), gv = tanhf(gpre);
      float c1;
      if (conse) {
        float ei = __expf(iv);
        float asum = ei;
        float csum = gv * ei;
        for (int k = 0; k < 2; ++k) {
          float cmk = (float)cons_mask[e * 2 + k];
          float apre = Xa[e * H_DIM + j] + ds_a[k * CH + tid];
          float al = __expf(sigf(apre)) * cmk;
          float cin = store[cons_idx[e * 2 + k] * H_DIM + j];
          asum += al;
          csum += cin * al;
        }
        c1 = csum / asum;
      } else {
        c1 = (1.f - iv) * prevc1[tid] + iv * gv;
      }
      float h1 = ov * tanhf(c1);
      prevc1[tid] = c1;
      out[e * H_DIM + j] = h1;
      out[T_LEN * H_DIM + e * H_DIM + j] = c1;
      Hbuf[e * H_DIM + j] = h1;
    }

    // ---- Phase D: all-gather h1[e].
    gbar(cnt, ++bc * NWG);
    h1s[tid] = Hbuf[e * H_DIM + tid];
    __syncthreads();
  }
}

extern "C" void kernel_launch(void* const* d_in, const int* in_sizes, int n_in,
                              void* d_out, int out_size, void* d_ws, size_t ws_size,
                              hipStream_t stream) {
  const float* x    = (const float*)d_in[0];
  const float* emb  = (const float*)d_in[1];
  const float* Wih  = (const float*)d_in[2];
  const float* Whh  = (const float*)d_in[3];
  const float* bias = (const float*)d_in[4];
  const float* aWih = (const float*)d_in[5];
  const float* aWhh = (const float*)d_in[6];
  const float* ab   = (const float*)d_in[7];
  const float* wWih = (const float*)d_in[8];
  const float* wWhh = (const float*)d_in[9];
  const float* wb   = (const float*)d_in[10];
  const int* prod_word = (const int*)d_in[11];
  const int* prod_dest = (const int*)d_in[12];
  const int* prod_mask = (const int*)d_in[13];
  const int* cons_idx  = (const int*)d_in[14];
  const int* cons_mask = (const int*)d_in[15];

  // workspace layout (floats)
  float* ws    = (float*)d_ws;
  float* Xg    = ws;                         // 512*1536
  float* Xa    = Xg + 512 * 1536;            // 512*512
  float* Wgx   = Xa + 512 * 512;             // 1024*1536
  float* Hbuf  = Wgx + 1024 * 1536;          // 512*512
  float* store = Hbuf + 512 * 512;           // 341*512
  unsigned* cnt = (unsigned*)(store + 341 * 512);
  size_t need = (size_t)(store + 341 * 512 - ws) * sizeof(float) + 64;
  if (ws_size < need) return;  // would corrupt memory; fail loudly via validation

  // zero skip-cell store + barrier counter (store0 = zeros in reference)
  hipMemsetAsync(store, 0, 341 * 512 * sizeof(float) + 64, stream);

  dim3 blk(256);
  proj_kernel<32><<<dim3(512 / 32, 1536 / 256), blk, 0, stream>>>(x, Wih, bias, Xg, nullptr, 1536);
  proj_kernel<32><<<dim3(512 / 32, 512 / 256),  blk, 0, stream>>>(x, aWih, ab, Xa, nullptr, 512);
  proj_kernel<32><<<dim3(1024 / 32, 1536 / 256), blk, 0, stream>>>(emb, wWih, wb, Wgx, prod_word, 1536);

  lattice_seq<<<dim3(NWG), dim3(NT), 0, stream>>>(
      Whh, aWhh, wWhh, Xg, Xa, Wgx,
      prod_mask, prod_dest, cons_idx, cons_mask,
      Hbuf, store, cnt, (float*)d_out);
}

// Round 2
// 2824.956 us; speedup vs baseline: 1.0641x; 1.0641x over previous
//
#include <hip/hip_runtime.h>
#include <stdint.h>

// LatticeLSTM on MI355X, round 2.
// - proj_fused: one launch computes Xg = x@Wih+b, Xa = x@aWih+ab, Wgx = emb[pw]@wWih+wb.
// - lattice_seq: 32 persistent WGs, register-resident recurrent weights,
//   per-WG epoch flags (no central barrier, no threadfence cache flushes),
//   all cross-WG data via agent-scope atomics (LLC-coherent, cache-bypass).

#define T_LEN 512
#define H_DIM 512
#define G3    1536
#define NWG   32
#define NT    512
#define CH    16
#define FS    32   // flag stride in dwords (128 B)

#define SCOPE_AGENT __HIP_MEMORY_SCOPE_AGENT

__device__ __forceinline__ float sigf(float x) { return 1.0f / (1.0f + __expf(-x)); }

// 128-MAC column dot-product: vec (LDS) * per-thread weight slice; 4-lane reduce.
// Thread group: lane = col*4 + ks, ks in [0,4). Result valid at ks==0.
__device__ __forceinline__ float mv128(const float* vec, const float* wr, int ks) {
  float acc = 0.f;
#pragma unroll
  for (int u = 0; u < 32; ++u) {
    float4 hv = *(const float4*)&vec[ks * 4 + u * 16];
    acc += hv.x * wr[u * 4] + hv.y * wr[u * 4 + 1] + hv.z * wr[u * 4 + 2] + hv.w * wr[u * 4 + 3];
  }
  acc += __shfl_down(acc, 2);
  acc += __shfl_down(acc, 1);
  return acc;
}

// ---------------- fused input projections ----------------
// blocks [0,96): Xg (512x1536); [96,128): Xa (512x512); [128,320): Wgx (1024x1536, gathered)
__global__ __launch_bounds__(256) void proj_fused(
    const float* __restrict__ x, const float* __restrict__ Wih, const float* __restrict__ bias,
    const float* __restrict__ aWih, const float* __restrict__ ab,
    const float* __restrict__ emb, const float* __restrict__ wWih, const float* __restrict__ wb,
    const int* __restrict__ prod_word,
    float* __restrict__ Xg, float* __restrict__ Xa, float* __restrict__ Wgx) {
  const int b = blockIdx.x;
  const float *A, *W, *bi;
  float* out;
  const int* gather = nullptr;
  int rt, N, cb;
  if (b < 96)       { A = x;   W = Wih;  bi = bias; out = Xg;  N = 1536; rt = (b / 6) * 32;        cb = (b % 6) * 256; }
  else if (b < 128) { int bb = b - 96;  A = x;   W = aWih; bi = ab; out = Xa;  N = 512;  rt = (bb / 2) * 32; cb = (bb % 2) * 256; }
  else              { int bb = b - 128; A = emb; W = wWih; bi = wb; out = Wgx; N = 1536; gather = prod_word; rt = (bb / 6) * 32; cb = (bb % 6) * 256; }
  __shared__ float As[32][256];
  const int tid = threadIdx.x;
  for (int rr = 0; rr < 32; ++rr) {
    int r = rt + rr;
    int src = gather ? gather[r] : r;
    As[rr][tid] = A[(long)src * 256 + tid];
  }
  __syncthreads();
  const int c = cb + tid;
  float acc[32];
#pragma unroll
  for (int rr = 0; rr < 32; ++rr) acc[rr] = 0.f;
#pragma unroll 4
  for (int k = 0; k < 256; ++k) {
    float wv = W[(long)k * N + c];
#pragma unroll
    for (int rr = 0; rr < 32; ++rr) acc[rr] += As[rr][k] * wv;
  }
  float bv = bi[c];
  for (int rr = 0; rr < 32; ++rr) out[(long)(rt + rr) * N + c] = acc[rr] + bv;
}

// ---------------- sequential lattice scan ----------------
__global__ __launch_bounds__(NT, 2) void lattice_seq(
    const float* __restrict__ Whh,   // 512 x 1536
    const float* __restrict__ aWhh,  // 512 x 512
    const float* __restrict__ wWhh,  // 512 x 1536
    const float* __restrict__ Xg,    // T x 1536 (bias folded)
    const float* __restrict__ Xa,    // T x 512  (alpha_bias folded)
    const float* __restrict__ Wgx,   // (T*2) x 1536 (w_bias folded)
    const int* __restrict__ prod_mask, const int* __restrict__ prod_dest,
    const int* __restrict__ cons_idx,  const int* __restrict__ cons_mask,
    float* __restrict__ store,   // (M+1) x 512 -- agent-atomic access only
    unsigned* __restrict__ flags, // NWG slots, stride FS dwords; zeroed pre-launch
    float* __restrict__ out)     // hs at [0,T*H) (agent-atomic), cs at [T*H, 2*T*H)
{
  const int tid = threadIdx.x;
  const int w = blockIdx.x;
  const int j0 = w * CH;
  float* outh = out;
  float* outc = out + (long)T_LEN * H_DIM;

  __shared__ float h1s[H_DIM];
  __shared__ float prevc1[CH];
  __shared__ float ds_g[3 * CH];
  __shared__ float ds_wg[3 * CH];
  __shared__ float ds_a[2 * CH];
  __shared__ float cins[2][H_DIM];

  // ---- register-resident weight slices: 128 floats/thread, r = ks*4 + u*16 + v.
  // G1 (tid<192):   Whh,  48 cols (3 gates x 16), ks = tid&3
  // G2 (tid<384):   wWhh, 48 cols,                ks = (tid-192)&3
  // G3 (tid>=384):  aWhh, 16 cols (both waves identical), ks = (tid&63)&3
  float wreg[128];
  int ks, dcol;
  {
    const float* Wsrc;
    int ldw, gcol;
    if (tid < 192) {
      dcol = tid >> 2; ks = tid & 3;
      Wsrc = Whh; ldw = G3; gcol = (dcol >> 4) * 512 + j0 + (dcol & 15);
    } else if (tid < 384) {
      int t = tid - 192; dcol = t >> 2; ks = t & 3;
      Wsrc = wWhh; ldw = G3; gcol = (dcol >> 4) * 512 + j0 + (dcol & 15);
    } else {
      int lane = tid & 63; dcol = lane >> 2; ks = lane & 3;
      Wsrc = aWhh; ldw = H_DIM; gcol = j0 + dcol;
    }
#pragma unroll
    for (int u = 0; u < 32; ++u)
#pragma unroll
      for (int v = 0; v < 4; ++v) {
        int r = ks * 4 + u * 16 + v;
        wreg[u * 4 + v] = Wsrc[(long)r * ldw + gcol];
      }
  }
  h1s[tid] = 0.f;
  if (tid < CH) prevc1[tid] = 0.f;
  __syncthreads();

  unsigned ep = 0;

  for (int e = 0; e < T_LEN; ++e) {
    const int p = e - 1;
    const bool prodp = (p >= 0) && ((prod_mask[p * 2] | prod_mask[p * 2 + 1]) != 0);
    const bool conse = (cons_mask[e * 2] | cons_mask[e * 2 + 1]) != 0;
    const unsigned epA2 = ep + 1;
    const unsigned epD = ep + (prodp ? 2u : 1u);

    // ---- prefetch per-step inputs (issued before any waiting; wave 0 only)
    float xg0 = 0, xg1 = 0, xg2 = 0, xa0 = 0, wg0 = 0, wg1 = 0, wg2 = 0;
    if (tid < 16) {
      int j = j0 + tid;
      xg0 = Xg[(long)e * G3 + j];
      xg1 = Xg[(long)e * G3 + 512 + j];
      xg2 = Xg[(long)e * G3 + 1024 + j];
      xa0 = Xa[(long)e * H_DIM + j];
    }
    if (prodp && tid < 32) {
      int k = tid >> 4, jj = tid & 15, r = p * 2 + k;
      wg0 = Wgx[(long)r * G3 + j0 + jj];
      wg1 = Wgx[(long)r * G3 + 512 + j0 + jj];
      wg2 = Wgx[(long)r * G3 + 1024 + j0 + jj];
    }

    // ---- top-of-step: wait for all WGs' D(e-1), then gather h1[e-1]
    if (e > 0) {
      if (tid < 64) {
        while (__hip_atomic_load(&flags[(tid & 31) * FS], __ATOMIC_RELAXED, SCOPE_AGENT) < ep) {}
      }
      __syncthreads();
      h1s[tid] = __hip_atomic_load(&outh[(long)p * H_DIM + tid], __ATOMIC_RELAXED, SCOPE_AGENT);
      __syncthreads();
    }

    // ---- concurrent matvecs
    if (tid < 192) {                       // main gates: h1[e-1] @ Whh
      float a = mv128(h1s, wreg, ks);
      if (ks == 0) ds_g[dcol] = a;
    } else if (tid < 384) {                // word gates: h1[p] @ wWhh (produce path)
      if (prodp) {
        float a = mv128(h1s, wreg, ks);
        if (ks == 0) ds_wg[dcol] = a;
      }
    } else if (conse && !prodp) {          // alpha path, all rows lag>=2: no wait needed
      const int lane = tid & 63;
      const int k = (tid >> 6) & 1;
      const long m = cons_idx[e * 2 + k];
      const float* row = store + m * H_DIM;
#pragma unroll
      for (int q = 0; q < 8; ++q) {
        int idx = q * 64 + lane;
        cins[k][idx] = __hip_atomic_load(row + idx, __ATOMIC_RELAXED, SCOPE_AGENT);
      }
      asm volatile("s_waitcnt lgkmcnt(0)" ::: "memory");
      __builtin_amdgcn_sched_barrier(0);
      float a = mv128(cins[k], wreg, ks);
      if (ks == 0) ds_a[k * CH + dcol] = a;
    }
    __syncthreads();  // sync1

    if (prodp) {
      if (tid < 32) {  // finalize word cells for step p; wave-0 stores
        int k = tid >> 4, jj = tid & 15, r = p * 2 + k;
        if (prod_mask[r]) {
          float f2 = wg0 + ds_wg[jj];
          float i2 = wg1 + ds_wg[16 + jj];
          float g2 = wg2 + ds_wg[32 + jj];
          float ct = sigf(f2) * prevc1[jj] + sigf(i2) * tanhf(g2);
          __hip_atomic_store(&store[(long)prod_dest[r] * H_DIM + j0 + jj], ct,
                             __ATOMIC_RELAXED, SCOPE_AGENT);
        }
      }
      if (tid == 0)  // release: wave-level vmcnt covers lanes 0..31's stores
        __hip_atomic_store(&flags[w * FS], epA2, __ATOMIC_RELEASE, SCOPE_AGENT);
      if (conse && tid >= 384) {  // alpha path with possible lag-1 rows
        const int lane = tid & 63;
        while (__hip_atomic_load(&flags[(lane & 31) * FS], __ATOMIC_ACQUIRE, SCOPE_AGENT) < epA2) {}
        const int k = (tid >> 6) & 1;
        const long m = cons_idx[e * 2 + k];
        const float* row = store + m * H_DIM;
#pragma unroll
        for (int q = 0; q < 8; ++q) {
          int idx = q * 64 + lane;
          cins[k][idx] = __hip_atomic_load(row + idx, __ATOMIC_RELAXED, SCOPE_AGENT);
        }
        asm volatile("s_waitcnt lgkmcnt(0)" ::: "memory");
        __builtin_amdgcn_sched_barrier(0);
        float a = mv128(cins[k], wreg, ks);
        if (ks == 0) ds_a[k * CH + dcol] = a;
      }
    }
    __syncthreads();  // sync2

    // ---- elementwise combine for owned H-chunk
    if (tid < 16) {
      int j = j0 + tid;
      float ipre = xg0 + ds_g[tid];
      float opre = xg1 + ds_g[16 + tid];
      float gpre = xg2 + ds_g[32 + tid];
      float iv = sigf(ipre), ov = sigf(opre), gv = tanhf(gpre);
      float c1;
      if (conse) {
        float ei = __expf(iv);
        float asum = ei, csum = gv * ei;
#pragma unroll
        for (int k = 0; k < 2; ++k) {
          float cmk = (float)cons_mask[e * 2 + k];
          float apre = xa0 + ds_a[k * CH + tid];
          float al = __expf(sigf(apre)) * cmk;
          asum += al;
          csum += cins[k][j] * al;
        }
        c1 = csum / asum;
      } else {
        c1 = (1.f - iv) * prevc1[tid] + iv * gv;
      }
      float h1 = ov * tanhf(c1);
      prevc1[tid] = c1;
      __hip_atomic_store(&outh[(long)e * H_DIM + j], h1, __ATOMIC_RELAXED, SCOPE_AGENT);
      outc[(long)e * H_DIM + j] = c1;
    }
    if (tid == 0)  // release: wave-level vmcnt covers lanes 0..15's h stores
      __hip_atomic_store(&flags[w * FS], epD, __ATOMIC_RELEASE, SCOPE_AGENT);
    ep = epD;
  }
}

extern "C" void kernel_launch(void* const* d_in, const int* in_sizes, int n_in,
                              void* d_out, int out_size, void* d_ws, size_t ws_size,
                              hipStream_t stream) {
  const float* x    = (const float*)d_in[0];
  const float* emb  = (const float*)d_in[1];
  const float* Wih  = (const float*)d_in[2];
  const float* Whh  = (const float*)d_in[3];
  const float* bias = (const float*)d_in[4];
  const float* aWih = (const float*)d_in[5];
  const float* aWhh = (const float*)d_in[6];
  const float* ab   = (const float*)d_in[7];
  const float* wWih = (const float*)d_in[8];
  const float* wWhh = (const float*)d_in[9];
  const float* wb   = (const float*)d_in[10];
  const int* prod_word = (const int*)d_in[11];
  const int* prod_dest = (const int*)d_in[12];
  const int* prod_mask = (const int*)d_in[13];
  const int* cons_idx  = (const int*)d_in[14];
  const int* cons_mask = (const int*)d_in[15];

  float* ws    = (float*)d_ws;
  float* Xg    = ws;                          // 512*1536
  float* Xa    = Xg + 512 * 1536;             // 512*512
  float* Wgx   = Xa + 512 * 512;              // 1024*1536
  float* store = Wgx + 1024 * 1536;           // 341*512
  unsigned* flags = (unsigned*)(store + 341 * 512);  // NWG*FS dwords
  size_t need = ((size_t)(341 * 512) + 512 * 1536 + 512 * 512 + 1024 * 1536 + NWG * FS) * 4;
  if (ws_size < need) return;

  // zero skip-cell store + epoch flags (deterministic across graph replays)
  hipMemsetAsync(store, 0, (341 * 512 + NWG * FS) * sizeof(float), stream);

  proj_fused<<<dim3(320), dim3(256), 0, stream>>>(
      x, Wih, bias, aWih, ab, emb, wWih, wb, prod_word, Xg, Xa, Wgx);

  lattice_seq<<<dim3(NWG), dim3(NT), 0, stream>>>(
      Whh, aWhh, wWhh, Xg, Xa, Wgx,
      prod_mask, prod_dest, cons_idx, cons_mask,
      store, flags, (float*)d_out);
}